// Round 8
// baseline (464.853 us; speedup 1.0000x reference)
//
#include <hip/hip_runtime.h>

#define BATCH 16
#define NNODES 50000
#define NEDGES 1600000
#define BN (BATCH * NNODES)
#define NPP 400       // nodes per partition; 125 * 400 = 50000 exactly
#define NPARTS 125
#define PST 17        // padded LDS stride (bank-conflict-free)
#define WQCAP 80      // per-wave queue capacity (drain when > WQCAP-64)
#define NCHUNK 3125   // NEDGES / 512 exactly
#define CLAMP_LO -10.0f
#define CLAMP_HI 10.0f
#define EPS_V 1e-6f

// ---- prep: o_pre (B,N) -> o_t (N,16); dst (int) -> dst16 (ushort) ----
__global__ void prep2_kernel(const float* __restrict__ o_pre,
                             const int* __restrict__ dst,
                             float* __restrict__ o_t,
                             unsigned short* __restrict__ dst16) {
    int t = blockIdx.x * blockDim.x + threadIdx.x;
    if (t < NNODES) {
        float v[BATCH];
#pragma unroll
        for (int b = 0; b < BATCH; ++b) v[b] = o_pre[b * NNODES + t];  // coalesced
        float4* op = (float4*)(o_t + (size_t)t * BATCH);
#pragma unroll
        for (int k = 0; k < 4; ++k)
            op[k] = make_float4(v[4 * k], v[4 * k + 1], v[4 * k + 2], v[4 * k + 3]);
    }
    if (t < NEDGES) dst16[t] = (unsigned short)dst[t];  // 50000 < 65536
}

// ---- fused scatter + epilogue: one block per node-partition ----
// No global atomics, no barriers in the edge loop. Each wave scans 512-edge
// chunks (8 edges/lane via one int4 of dst16), compacts matches into its own
// LDS queue with ballot-prefix (wave-uniform count in registers), and drains
// densely: 64B o_t row gather + 16 LDS fp32 atomics into the gj tile.
__global__ __launch_bounds__(1024, 4) void scatter_fused(
    const float* __restrict__ o_t,
    const unsigned short* __restrict__ dst16,
    const int* __restrict__ src,
    const float* __restrict__ w,
    const float* __restrict__ E,
    const float* __restrict__ chem,
    const float* __restrict__ threshold,
    const float* __restrict__ decay,
    float* __restrict__ out_o,
    float* __restrict__ out_e) {
    __shared__ float gj[NPP * PST];      // 27,200 B
    __shared__ float Et[NPP * PST];      // 27,200 B
    __shared__ uint2 wq[16 * WQCAP];     // 10,240 B  -> total 64,640 B

    const int tid = threadIdx.x;
    const int wid = tid >> 6;
    const int lane = tid & 63;
    const int base = blockIdx.x * NPP;

    // init: zero gj, load E tile (coalesced per b)
    for (int i = tid; i < NPP * PST; i += 1024) gj[i] = 0.0f;
    for (int i = tid; i < NPP * BATCH; i += 1024) {
        int b = i / NPP, n = i - b * NPP;
        Et[n * PST + b] = E[b * NNODES + base + n];
    }
    __syncthreads();

    uint2* __restrict__ myq = wq + wid * WQCAP;
    int qcount = 0;  // wave-uniform (all lanes compute identical value)

    for (int c = wid; c < NCHUNK; c += 16) {
        const int e_base = c * 512 + lane * 8;
        int4 pk = *(const int4*)(dst16 + e_base);  // 8 dsts, 16B aligned
        unsigned uw[4] = {(unsigned)pk.x, (unsigned)pk.y, (unsigned)pk.z, (unsigned)pk.w};
#pragma unroll
        for (int j = 0; j < 8; ++j) {
            unsigned d = (uw[j >> 1] >> ((j & 1) * 16)) & 0xFFFFu;
            unsigned local = d - (unsigned)base;
            bool pred = (local < (unsigned)NPP);
            unsigned long long mask = __ballot(pred);
            if (mask) {
                if (pred) {
                    int pre = __popcll(mask & ((1ull << lane) - 1ull));
                    int e = e_base + j;
                    myq[qcount + pre] =
                        make_uint2((unsigned)src[e] | (local << 16), __float_as_uint(w[e]));
                }
                qcount += (int)__popcll(mask);
                if (qcount > WQCAP - 64) {
                    // drain (all lanes; <= 2 strided steps)
                    for (int i = lane; i < qcount; i += 64) {
                        uint2 p = myq[i];
                        unsigned s = p.x & 0xFFFFu;
                        int l17 = (int)(p.x >> 16) * PST;
                        float wv = __uint_as_float(p.y);
                        const float4* orow = (const float4*)(o_t + (size_t)s * BATCH);
                        float4 r0 = orow[0], r1 = orow[1], r2 = orow[2], r3 = orow[3];
                        float oj[16] = {r0.x, r0.y, r0.z, r0.w, r1.x, r1.y, r1.z, r1.w,
                                        r2.x, r2.y, r2.z, r2.w, r3.x, r3.y, r3.z, r3.w};
#pragma unroll
                        for (int b = 0; b < 16; ++b) {
                            float en = Et[l17 + b];
                            float cv = (oj[b] >= en) ? oj[b] * wv : -oj[b] * wv;
                            atomicAdd(&gj[l17 + b], cv);
                        }
                    }
                    qcount = 0;
                }
            }
        }
    }
    // final drain
    for (int i = lane; i < qcount; i += 64) {
        uint2 p = myq[i];
        unsigned s = p.x & 0xFFFFu;
        int l17 = (int)(p.x >> 16) * PST;
        float wv = __uint_as_float(p.y);
        const float4* orow = (const float4*)(o_t + (size_t)s * BATCH);
        float4 r0 = orow[0], r1 = orow[1], r2 = orow[2], r3 = orow[3];
        float oj[16] = {r0.x, r0.y, r0.z, r0.w, r1.x, r1.y, r1.z, r1.w,
                        r2.x, r2.y, r2.z, r2.w, r3.x, r3.y, r3.z, r3.w};
#pragma unroll
        for (int b = 0; b < 16; ++b) {
            float en = Et[l17 + b];
            float cv = (oj[b] >= en) ? oj[b] * wv : -oj[b] * wv;
            atomicAdd(&gj[l17 + b], cv);
        }
    }
    __syncthreads();

    // fused epilogue: coalesced global reads/writes, LDS gj/Et reads
    for (int i = tid; i < NPP * BATCH; i += 1024) {
        int b = i / NPP, n = i - b * NPP;
        int g = b * NNODES + base + n;
        float e = Et[n * PST + b];
        float S = e + chem[g] + gj[n * PST + b];
        S = fminf(fmaxf(S, CLAMP_LO), CLAMP_HI);
        float th = threshold[base + n];
        float no = fmaxf(S - th, 0.0f);
        float ne;
        if (S > th) ne = no;
        else if (fabsf(S - e) <= EPS_V) ne = e - decay[base + n];
        else ne = S;
        out_o[g] = no;
        out_e[g] = ne;
    }
}

// ---------- Fallback: device-scope atomic path (needs no workspace) ----------
__global__ void edge_scatter_dev(const float* __restrict__ o_pre, const float* __restrict__ E,
                                 const float* __restrict__ w, const int* __restrict__ src,
                                 const int* __restrict__ dst, float* __restrict__ gj) {
    int e = blockIdx.x * blockDim.x + threadIdx.x;
    if (e >= NEDGES) return;
    int s = src[e];
    int d = dst[e];
    float wv = w[e];
#pragma unroll
    for (int b = 0; b < BATCH; ++b) {
        float oj = o_pre[b * NNODES + s];
        float en = E[b * NNODES + d];
        atomicAdd(&gj[b * NNODES + d], (oj >= en) ? oj * wv : -oj * wv);
    }
}

__global__ void finalize_dev(const float* __restrict__ chem, const float* __restrict__ E,
                             const float* __restrict__ threshold, const float* __restrict__ decay,
                             float* __restrict__ out_o, float* __restrict__ out_e_gj) {
    int i = blockIdx.x * blockDim.x + threadIdx.x;
    if (i >= BN) return;
    int n = i % NNODES;
    float e = E[i];
    float S = e + chem[i] + out_e_gj[i];
    S = fminf(fmaxf(S, CLAMP_LO), CLAMP_HI);
    float th = threshold[n];
    float no = fmaxf(S - th, 0.0f);
    float ne;
    if (S > th) ne = no;
    else if (fabsf(S - e) <= EPS_V) ne = e - decay[n];
    else ne = S;
    out_o[i] = no;
    out_e_gj[i] = ne;
}

extern "C" void kernel_launch(void* const* d_in, const int* in_sizes, int n_in,
                              void* d_out, int out_size, void* d_ws, size_t ws_size,
                              hipStream_t stream) {
    const float* chem      = (const float*)d_in[0];
    const float* E         = (const float*)d_in[1];
    const float* o_pre     = (const float*)d_in[2];
    const float* w         = (const float*)d_in[3];
    const float* threshold = (const float*)d_in[4];
    const float* decay     = (const float*)d_in[5];
    const int*   src       = (const int*)d_in[6];
    const int*   dst       = (const int*)d_in[7];

    float* out_o = (float*)d_out;
    float* out_e = (float*)d_out + BN;

    const int block = 256;

    // ws layout: o_t (N*16 floats = 3.2MB) | dst16 (EDGES ushorts = 3.2MB)
    const size_t OT_OFF  = 0;
    const size_t D16_OFF = 3200000;  // 16B aligned
    const size_t need    = D16_OFF + (size_t)NEDGES * sizeof(unsigned short);

    if (ws_size >= need) {
        char* ws = (char*)d_ws;
        float*          o_t   = (float*)(ws + OT_OFF);
        unsigned short* dst16 = (unsigned short*)(ws + D16_OFF);

        int grid_prep = (NEDGES + block - 1) / block;
        prep2_kernel<<<grid_prep, block, 0, stream>>>(o_pre, dst, o_t, dst16);

        scatter_fused<<<NPARTS, 1024, 0, stream>>>(o_t, dst16, src, w, E, chem,
                                                   threshold, decay, out_o, out_e);
    } else {
        hipMemsetAsync(out_e, 0, (size_t)BN * sizeof(float), stream);
        int grid_e = (NEDGES + block - 1) / block;
        edge_scatter_dev<<<grid_e, block, 0, stream>>>(o_pre, E, w, src, dst, out_e);
        int grid_bn = (BN + block - 1) / block;
        finalize_dev<<<grid_bn, block, 0, stream>>>(chem, E, threshold, decay, out_o, out_e);
    }
}

// Round 9
// 292.826 us; speedup vs baseline: 1.5875x; 1.5875x over previous
//
#include <hip/hip_runtime.h>

#define BATCH 16
#define NNODES 50000
#define NEDGES 1600000
#define BN (BATCH * NNODES)
#define EPB 4096                 // edges per binning block
#define NBLK 391                 // ceil(NEDGES / EPB)
#define BSZ 256                  // nodes per bin
#define NBINS 196                // ceil(NNODES / BSZ); last bin has 80 nodes
#define PST 17                   // padded LDS row stride (spreads banks)
#define CLAMP_LO -10.0f
#define CLAMP_HI 10.0f
#define EPS_V 1e-6f

// ---- transpose o_pre (B,N) -> o_t (N,16) ----
__global__ void transpose_kernel(const float* __restrict__ o_pre,
                                 float* __restrict__ o_t) {
    int t = blockIdx.x * blockDim.x + threadIdx.x;
    if (t >= NNODES) return;
    float v[BATCH];
#pragma unroll
    for (int b = 0; b < BATCH; ++b) v[b] = o_pre[b * NNODES + t];  // coalesced
    float4* op = (float4*)(o_t + (size_t)t * BATCH);
#pragma unroll
    for (int k = 0; k < 4; ++k)
        op[k] = make_float4(v[4 * k], v[4 * k + 1], v[4 * k + 2], v[4 * k + 3]);
}

// ---- pass 1a: per-block histogram of coarse bins (dst>>8) ----
__global__ void hist_kernel(const int* __restrict__ dst,
                            int* __restrict__ hist) {
    __shared__ int lh[NBINS];
    int t = threadIdx.x;
    for (int i = t; i < NBINS; i += 256) lh[i] = 0;
    __syncthreads();
    int eb = blockIdx.x * EPB;
#pragma unroll
    for (int j = 0; j < 16; ++j) {
        int e = eb + j * 256 + t;
        if (e < NEDGES) atomicAdd(&lh[dst[e] >> 8], 1);
    }
    __syncthreads();
    for (int i = t; i < NBINS; i += 256) hist[i * NBLK + blockIdx.x] = lh[i];
}

// ---- pass 1b: per-bin exclusive scan over blocks (196 blocks, 391 vals each) ----
__global__ void scanA_kernel(int* __restrict__ hist, int* __restrict__ totals) {
    __shared__ int sm[512];
    int k = blockIdx.x, t = threadIdx.x;
    int v0 = (t < NBLK) ? hist[k * NBLK + t] : 0;
    int v1 = (256 + t < NBLK) ? hist[k * NBLK + 256 + t] : 0;
    sm[t] = v0;
    sm[256 + t] = v1;
    __syncthreads();
    for (int off = 1; off < 512; off <<= 1) {
        int a = (t >= off) ? sm[t - off] : 0;
        int b = (256 + t >= off) ? sm[256 + t - off] : 0;
        __syncthreads();
        sm[t] += a;
        sm[256 + t] += b;
        __syncthreads();
    }
    if (t < NBLK) hist[k * NBLK + t] = sm[t] - v0;                  // exclusive
    if (256 + t < NBLK) hist[k * NBLK + 256 + t] = sm[256 + t] - v1;
    if (t == 0) totals[k] = sm[NBLK - 1];
}

// ---- pass 1c: scan bin totals -> bin base offsets (1 block) ----
__global__ void scanB_kernel(const int* __restrict__ totals,
                             int* __restrict__ base) {
    __shared__ int sm[256];
    int t = threadIdx.x;
    int v = (t < NBINS) ? totals[t] : 0;
    sm[t] = v;
    __syncthreads();
    for (int off = 1; off < 256; off <<= 1) {
        int a = (t >= off) ? sm[t - off] : 0;
        __syncthreads();
        sm[t] += a;
        __syncthreads();
    }
    if (t < NBINS) base[t] = sm[t] - v;       // exclusive
    if (t == 0) base[NBINS] = sm[NBINS - 1];  // total = NEDGES
}

// ---- pass 1d: scatter edges into bin-contiguous array, deterministic slots ----
// LDS cursors seeded with base[bin] + per-block prefix: zero global atomics.
__global__ void scatterA_kernel(const int* __restrict__ src,
                                const int* __restrict__ dst,
                                const float* __restrict__ w,
                                const int* __restrict__ hist,
                                const int* __restrict__ base,
                                uint2* __restrict__ binned) {
    __shared__ int cur[NBINS];
    int t = threadIdx.x;
    for (int i = t; i < NBINS; i += 256)
        cur[i] = base[i] + hist[i * NBLK + blockIdx.x];
    __syncthreads();
    int eb = blockIdx.x * EPB;
#pragma unroll
    for (int j = 0; j < 16; ++j) {
        int e = eb + j * 256 + t;
        if (e < NEDGES) {
            int d = dst[e];
            int bin = d >> 8;
            int pos = atomicAdd(&cur[bin], 1);  // LDS atomic
            binned[pos] = make_uint2((unsigned)src[e] | ((unsigned)(d & 255) << 16),
                                     __float_as_uint(w[e]));
        }
    }
}

// ---- pass 2: one block per bin — coalesced edge reads, LDS gj accumulate,
//      fused epilogue. (Numerics validated by round-8's passing kernel.) ----
__global__ __launch_bounds__(1024) void bin_gather(
    const float* __restrict__ o_t,
    const float* __restrict__ E,
    const float* __restrict__ chem,
    const float* __restrict__ threshold,
    const float* __restrict__ decay,
    const int* __restrict__ base,
    const uint2* __restrict__ binned,
    float* __restrict__ out_o,
    float* __restrict__ out_e) {
    __shared__ float gj[BSZ * PST];  // 17,408 B
    __shared__ float Et[BSZ * PST];  // 17,408 B
    const int k = blockIdx.x, tid = threadIdx.x;
    const int node0 = k * BSZ;
    const int nn = (NNODES - node0 < BSZ) ? (NNODES - node0) : BSZ;

    for (int i = tid; i < BSZ * PST; i += 1024) gj[i] = 0.0f;
    for (int i = tid; i < nn * BATCH; i += 1024) {
        int b = i / nn, n = i - b * nn;
        Et[n * PST + b] = E[b * NNODES + node0 + n];  // coalesced per b
    }
    __syncthreads();

    const int s0 = base[k], s1 = base[k + 1];
    for (int i = s0 + tid; i < s1; i += 1024) {
        uint2 p = binned[i];  // coalesced
        int s = (int)(p.x & 0xFFFFu);
        int l = (int)((p.x >> 16) & 0xFFu) * PST;
        float wv = __uint_as_float(p.y);
        const float4* orow = (const float4*)(o_t + (size_t)s * BATCH);
        float4 r0 = orow[0], r1 = orow[1], r2 = orow[2], r3 = orow[3];
        float oj[16] = {r0.x, r0.y, r0.z, r0.w, r1.x, r1.y, r1.z, r1.w,
                        r2.x, r2.y, r2.z, r2.w, r3.x, r3.y, r3.z, r3.w};
#pragma unroll
        for (int b = 0; b < 16; ++b) {
            float en = Et[l + b];
            atomicAdd(&gj[l + b], (oj[b] >= en) ? oj[b] * wv : -oj[b] * wv);
        }
    }
    __syncthreads();

    for (int i = tid; i < nn * BATCH; i += 1024) {
        int b = i / nn, n = i - b * nn;
        int g = b * NNODES + node0 + n;
        float e = Et[n * PST + b];
        float S = e + chem[g] + gj[n * PST + b];
        S = fminf(fmaxf(S, CLAMP_LO), CLAMP_HI);
        float th = threshold[node0 + n];
        float no = fmaxf(S - th, 0.0f);
        float ne;
        if (S > th) ne = no;
        else if (fabsf(S - e) <= EPS_V) ne = e - decay[node0 + n];
        else ne = S;
        out_o[g] = no;
        out_e[g] = ne;
    }
}

// ---------- Fallback: device-scope atomic path (needs no workspace) ----------
__global__ void edge_scatter_dev(const float* __restrict__ o_pre, const float* __restrict__ E,
                                 const float* __restrict__ w, const int* __restrict__ src,
                                 const int* __restrict__ dst, float* __restrict__ gj) {
    int e = blockIdx.x * blockDim.x + threadIdx.x;
    if (e >= NEDGES) return;
    int s = src[e];
    int d = dst[e];
    float wv = w[e];
#pragma unroll
    for (int b = 0; b < BATCH; ++b) {
        float oj = o_pre[b * NNODES + s];
        float en = E[b * NNODES + d];
        atomicAdd(&gj[b * NNODES + d], (oj >= en) ? oj * wv : -oj * wv);
    }
}

__global__ void finalize_dev(const float* __restrict__ chem, const float* __restrict__ E,
                             const float* __restrict__ threshold, const float* __restrict__ decay,
                             float* __restrict__ out_o, float* __restrict__ out_e_gj) {
    int i = blockIdx.x * blockDim.x + threadIdx.x;
    if (i >= BN) return;
    int n = i % NNODES;
    float e = E[i];
    float S = e + chem[i] + out_e_gj[i];
    S = fminf(fmaxf(S, CLAMP_LO), CLAMP_HI);
    float th = threshold[n];
    float no = fmaxf(S - th, 0.0f);
    float ne;
    if (S > th) ne = no;
    else if (fabsf(S - e) <= EPS_V) ne = e - decay[n];
    else ne = S;
    out_o[i] = no;
    out_e_gj[i] = ne;
}

extern "C" void kernel_launch(void* const* d_in, const int* in_sizes, int n_in,
                              void* d_out, int out_size, void* d_ws, size_t ws_size,
                              hipStream_t stream) {
    const float* chem      = (const float*)d_in[0];
    const float* E         = (const float*)d_in[1];
    const float* o_pre     = (const float*)d_in[2];
    const float* w         = (const float*)d_in[3];
    const float* threshold = (const float*)d_in[4];
    const float* decay     = (const float*)d_in[5];
    const int*   src       = (const int*)d_in[6];
    const int*   dst       = (const int*)d_in[7];

    float* out_o = (float*)d_out;
    float* out_e = (float*)d_out + BN;

    // ws layout (bytes):
    //   o_t:    [0,          3,200,000)   N*16 floats
    //   binned: [3,200,000, 16,000,000)   EDGES uint2
    //   hist:   [16,000,000, 16,306,544)  NBINS*NBLK ints
    //   totals: [16,306,560, 16,307,344)  NBINS ints
    //   base:   [16,307,360, 16,308,148)  NBINS+1 ints
    const size_t OT_OFF  = 0;
    const size_t BIN_OFF = 3200000;
    const size_t H_OFF   = 16000000;
    const size_t TOT_OFF = 16306560;
    const size_t BAS_OFF = 16307360;
    const size_t need    = BAS_OFF + (size_t)(NBINS + 1) * sizeof(int);

    if (ws_size >= need) {
        char* ws = (char*)d_ws;
        float* o_t    = (float*)(ws + OT_OFF);
        uint2* binned = (uint2*)(ws + BIN_OFF);
        int*   hist   = (int*)(ws + H_OFF);
        int*   totals = (int*)(ws + TOT_OFF);
        int*   base   = (int*)(ws + BAS_OFF);

        transpose_kernel<<<(NNODES + 255) / 256, 256, 0, stream>>>(o_pre, o_t);
        hist_kernel<<<NBLK, 256, 0, stream>>>(dst, hist);
        scanA_kernel<<<NBINS, 256, 0, stream>>>(hist, totals);
        scanB_kernel<<<1, 256, 0, stream>>>(totals, base);
        scatterA_kernel<<<NBLK, 256, 0, stream>>>(src, dst, w, hist, base, binned);
        bin_gather<<<NBINS, 1024, 0, stream>>>(o_t, E, chem, threshold, decay,
                                               base, binned, out_o, out_e);
    } else {
        hipMemsetAsync(out_e, 0, (size_t)BN * sizeof(float), stream);
        edge_scatter_dev<<<(NEDGES + 255) / 256, 256, 0, stream>>>(o_pre, E, w, src, dst, out_e);
        finalize_dev<<<(BN + 255) / 256, 256, 0, stream>>>(chem, E, threshold, decay, out_o, out_e);
    }
}

// Round 10
// 150.855 us; speedup vs baseline: 3.0815x; 1.9411x over previous
//
#include <hip/hip_runtime.h>

#define BATCH 16
#define NNODES 50000
#define NEDGES 1600000
#define BN (BATCH * NNODES)
#define EPB 8192                 // edges per binning block
#define NBLK 196                 // ceil(NEDGES / EPB)
#define BSZ 128                  // nodes per bin
#define NBINS 391                // ceil(NNODES / BSZ); last bin has 80 nodes
#define CAPE 4992                // per-bin edge capacity (mean 4096, sd 64 -> +14 sd)
#define CLAMP_LO -10.0f
#define CLAMP_HI 10.0f
#define EPS_V 1e-6f

// ---- transpose o_pre,E (B,N) -> (N,16) ----
__global__ void transpose_kernel(const float* __restrict__ o_pre,
                                 const float* __restrict__ E,
                                 float* __restrict__ o_t,
                                 float* __restrict__ E_t) {
    int t = blockIdx.x * blockDim.x + threadIdx.x;
    if (t >= NNODES) return;
    float v[BATCH], u[BATCH];
#pragma unroll
    for (int b = 0; b < BATCH; ++b) {
        v[b] = o_pre[b * NNODES + t];  // coalesced
        u[b] = E[b * NNODES + t];
    }
    float4* op = (float4*)(o_t + (size_t)t * BATCH);
    float4* ep = (float4*)(E_t + (size_t)t * BATCH);
#pragma unroll
    for (int k = 0; k < 4; ++k) {
        op[k] = make_float4(v[4 * k], v[4 * k + 1], v[4 * k + 2], v[4 * k + 3]);
        ep[k] = make_float4(u[4 * k], u[4 * k + 1], u[4 * k + 2], u[4 * k + 3]);
    }
}

// ---- pass 1a: per-block histogram of coarse bins (dst>>7) ----
__global__ void hist_kernel(const int* __restrict__ dst,
                            int* __restrict__ hist) {
    __shared__ int lh[NBINS];
    int t = threadIdx.x;
    for (int i = t; i < NBINS; i += 256) lh[i] = 0;
    __syncthreads();
    int eb = blockIdx.x * EPB;
#pragma unroll
    for (int j = 0; j < 32; ++j) {
        int e = eb + j * 256 + t;
        if (e < NEDGES) atomicAdd(&lh[dst[e] >> 7], 1);
    }
    __syncthreads();
    for (int i = t; i < NBINS; i += 256) hist[i * NBLK + blockIdx.x] = lh[i];
}

// ---- pass 1b: per-bin exclusive scan over the 196 block counts ----
__global__ void scanA_kernel(int* __restrict__ hist, int* __restrict__ totals) {
    __shared__ int sm[256];
    int k = blockIdx.x, t = threadIdx.x;
    int v = (t < NBLK) ? hist[k * NBLK + t] : 0;
    sm[t] = v;
    __syncthreads();
    for (int off = 1; off < 256; off <<= 1) {
        int a = (t >= off) ? sm[t - off] : 0;
        __syncthreads();
        sm[t] += a;
        __syncthreads();
    }
    if (t < NBLK) hist[k * NBLK + t] = sm[t] - v;  // exclusive
    if (t == 0) totals[k] = sm[NBLK - 1];
}

// ---- pass 1c: scan the 391 bin totals -> bin base offsets (1 block) ----
__global__ void scanB_kernel(const int* __restrict__ totals,
                             int* __restrict__ base) {
    __shared__ int sm[512];
    int t = threadIdx.x;
    int v = (t < NBINS) ? totals[t] : 0;
    sm[t] = v;
    __syncthreads();
    for (int off = 1; off < 512; off <<= 1) {
        int a = (t >= off) ? sm[t - off] : 0;
        __syncthreads();
        sm[t] += a;
        __syncthreads();
    }
    if (t < NBINS) base[t] = sm[t] - v;       // exclusive
    if (t == 0) base[NBINS] = sm[NBINS - 1];  // total = NEDGES
}

// ---- pass 1d: scatter edges bin-contiguously, deterministic slots ----
__global__ void scatterA_kernel(const int* __restrict__ src,
                                const int* __restrict__ dst,
                                const float* __restrict__ w,
                                const int* __restrict__ hist,
                                const int* __restrict__ base,
                                uint2* __restrict__ binned) {
    __shared__ int cur[NBINS];
    int t = threadIdx.x;
    for (int i = t; i < NBINS; i += 256)
        cur[i] = base[i] + hist[i * NBLK + blockIdx.x];
    __syncthreads();
    int eb = blockIdx.x * EPB;
#pragma unroll
    for (int j = 0; j < 32; ++j) {
        int e = eb + j * 256 + t;
        if (e < NEDGES) {
            int d = dst[e];
            int pos = atomicAdd(&cur[d >> 7], 1);  // LDS atomic
            binned[pos] = make_uint2((unsigned)src[e] | ((unsigned)(d & 127) << 16),
                                     __float_as_uint(w[e]));
        }
    }
}

// ---- pass 2: per-bin node sub-sort in LDS, register accumulation, epilogue ----
__global__ __launch_bounds__(512) void bin_gather2(
    const float* __restrict__ o_t,
    const float* __restrict__ E_t,
    const float* __restrict__ chem,
    const float* __restrict__ threshold,
    const float* __restrict__ decay,
    const int* __restrict__ base,
    const uint2* __restrict__ binned,
    float* __restrict__ out_o,
    float* __restrict__ out_e) {
    __shared__ int   cnt_l[BSZ];   // per-node count -> cursor
    __shared__ int   offs[BSZ + 1];
    __shared__ int   sc[BSZ];
    __shared__ uint2 eb[CAPE];     // node-sorted edges of this bin (~40 KB)

    const int k = blockIdx.x, tid = threadIdx.x;
    const int node0 = k * BSZ;
    const int nn = (NNODES - node0 < BSZ) ? (NNODES - node0) : BSZ;
    const int s0 = base[k], s1 = base[k + 1];

    // A1: per-node histogram
    if (tid < BSZ) cnt_l[tid] = 0;
    __syncthreads();
    for (int i = s0 + tid; i < s1; i += 512)
        atomicAdd(&cnt_l[(binned[i].x >> 16) & 127], 1);
    __syncthreads();

    // A2: exclusive scan of 128 counts
    if (tid < BSZ) sc[tid] = cnt_l[tid];
    __syncthreads();
    for (int o = 1; o < BSZ; o <<= 1) {
        int v = (tid >= o && tid < BSZ) ? sc[tid - o] : 0;
        __syncthreads();
        if (tid < BSZ) sc[tid] += v;
        __syncthreads();
    }
    if (tid < BSZ) {
        int ex = sc[tid] - cnt_l[tid];
        offs[tid] = ex;
        cnt_l[tid] = ex;  // cursor
    }
    if (tid == 0) offs[BSZ] = s1 - s0;
    __syncthreads();

    // A3: scatter into node-sorted LDS array
    for (int i = s0 + tid; i < s1; i += 512) {
        uint2 p = binned[i];
        int pos = atomicAdd(&cnt_l[(p.x >> 16) & 127], 1);
        if (pos < CAPE) eb[pos] = p;
    }
    __syncthreads();

    // B+C: one thread per (node, batch-quad); register accumulation; epilogue
    for (int t = tid; t < nn * 4; t += 512) {
        int n = t >> 2;
        int q = (t & 3) * 4;
        int gn = node0 + n;
        int e0 = offs[n], e1 = offs[n + 1];
        float4 en = *(const float4*)(E_t + (size_t)gn * BATCH + q);
        float4 acc = make_float4(0.f, 0.f, 0.f, 0.f);
        for (int i = e0; i < e1; ++i) {
            uint2 p = eb[i];  // 4 lanes of the quad: same address -> broadcast
            float wv = __uint_as_float(p.y);
            int s = (int)(p.x & 0xFFFFu);
            float4 oj = *(const float4*)(o_t + (size_t)s * BATCH + q);
            acc.x += (oj.x >= en.x) ? oj.x * wv : -oj.x * wv;
            acc.y += (oj.y >= en.y) ? oj.y * wv : -oj.y * wv;
            acc.z += (oj.z >= en.z) ? oj.z * wv : -oj.z * wv;
            acc.w += (oj.w >= en.w) ? oj.w * wv : -oj.w * wv;
        }
        float th = threshold[gn];
        float dc = decay[gn];
        float ev[4] = {en.x, en.y, en.z, en.w};
        float av[4] = {acc.x, acc.y, acc.z, acc.w};
#pragma unroll
        for (int j = 0; j < 4; ++j) {
            int b = q + j;
            float e = ev[j];
            float S = e + chem[b * NNODES + gn] + av[j];
            S = fminf(fmaxf(S, CLAMP_LO), CLAMP_HI);
            float no = fmaxf(S - th, 0.0f);
            float ne;
            if (S > th) ne = no;
            else if (fabsf(S - e) <= EPS_V) ne = e - dc;
            else ne = S;
            out_o[b * NNODES + gn] = no;
            out_e[b * NNODES + gn] = ne;
        }
    }
}

// ---------- Fallback: device-scope atomic path (needs no workspace) ----------
__global__ void edge_scatter_dev(const float* __restrict__ o_pre, const float* __restrict__ E,
                                 const float* __restrict__ w, const int* __restrict__ src,
                                 const int* __restrict__ dst, float* __restrict__ gj) {
    int e = blockIdx.x * blockDim.x + threadIdx.x;
    if (e >= NEDGES) return;
    int s = src[e];
    int d = dst[e];
    float wv = w[e];
#pragma unroll
    for (int b = 0; b < BATCH; ++b) {
        float oj = o_pre[b * NNODES + s];
        float en = E[b * NNODES + d];
        atomicAdd(&gj[b * NNODES + d], (oj >= en) ? oj * wv : -oj * wv);
    }
}

__global__ void finalize_dev(const float* __restrict__ chem, const float* __restrict__ E,
                             const float* __restrict__ threshold, const float* __restrict__ decay,
                             float* __restrict__ out_o, float* __restrict__ out_e_gj) {
    int i = blockIdx.x * blockDim.x + threadIdx.x;
    if (i >= BN) return;
    int n = i % NNODES;
    float e = E[i];
    float S = e + chem[i] + out_e_gj[i];
    S = fminf(fmaxf(S, CLAMP_LO), CLAMP_HI);
    float th = threshold[n];
    float no = fmaxf(S - th, 0.0f);
    float ne;
    if (S > th) ne = no;
    else if (fabsf(S - e) <= EPS_V) ne = e - decay[n];
    else ne = S;
    out_o[i] = no;
    out_e_gj[i] = ne;
}

extern "C" void kernel_launch(void* const* d_in, const int* in_sizes, int n_in,
                              void* d_out, int out_size, void* d_ws, size_t ws_size,
                              hipStream_t stream) {
    const float* chem      = (const float*)d_in[0];
    const float* E         = (const float*)d_in[1];
    const float* o_pre     = (const float*)d_in[2];
    const float* w         = (const float*)d_in[3];
    const float* threshold = (const float*)d_in[4];
    const float* decay     = (const float*)d_in[5];
    const int*   src       = (const int*)d_in[6];
    const int*   dst       = (const int*)d_in[7];

    float* out_o = (float*)d_out;
    float* out_e = (float*)d_out + BN;

    // ws layout (bytes, 16B-aligned):
    //   o_t:    [0,          3,200,000)
    //   E_t:    [3,200,000,  6,400,000)
    //   binned: [6,400,000, 19,200,000)   EDGES uint2
    //   hist:   [19,200,000, 19,506,544)  NBINS*NBLK ints
    //   totals: [19,506,560, 19,508,124)  NBINS ints
    //   base:   [19,508,128, 19,509,696)  NBINS+1 ints
    const size_t OT_OFF  = 0;
    const size_t ET_OFF  = 3200000;
    const size_t BIN_OFF = 6400000;
    const size_t H_OFF   = 19200000;
    const size_t TOT_OFF = 19506560;
    const size_t BAS_OFF = 19508128;
    const size_t need    = BAS_OFF + (size_t)(NBINS + 1) * sizeof(int);

    if (ws_size >= need) {
        char* ws = (char*)d_ws;
        float* o_t    = (float*)(ws + OT_OFF);
        float* E_t    = (float*)(ws + ET_OFF);
        uint2* binned = (uint2*)(ws + BIN_OFF);
        int*   hist   = (int*)(ws + H_OFF);
        int*   totals = (int*)(ws + TOT_OFF);
        int*   base   = (int*)(ws + BAS_OFF);

        transpose_kernel<<<(NNODES + 255) / 256, 256, 0, stream>>>(o_pre, E, o_t, E_t);
        hist_kernel<<<NBLK, 256, 0, stream>>>(dst, hist);
        scanA_kernel<<<NBINS, 256, 0, stream>>>(hist, totals);
        scanB_kernel<<<1, 512, 0, stream>>>(totals, base);
        scatterA_kernel<<<NBLK, 256, 0, stream>>>(src, dst, w, hist, base, binned);
        bin_gather2<<<NBINS, 512, 0, stream>>>(o_t, E_t, chem, threshold, decay,
                                               base, binned, out_o, out_e);
    } else {
        hipMemsetAsync(out_e, 0, (size_t)BN * sizeof(float), stream);
        edge_scatter_dev<<<(NEDGES + 255) / 256, 256, 0, stream>>>(o_pre, E, w, src, dst, out_e);
        finalize_dev<<<(BN + 255) / 256, 256, 0, stream>>>(chem, E, threshold, decay, out_o, out_e);
    }
}

// Round 11
// 132.259 us; speedup vs baseline: 3.5147x; 1.1406x over previous
//
#include <hip/hip_runtime.h>

#define BATCH 16
#define NNODES 50000
#define NEDGES 1600000
#define BN (BATCH * NNODES)
#define NBLK 196                 // binning blocks; 196*8192 >= NEDGES
#define EPB 8192                 // edges per binning block
#define BSZ 128                  // nodes per bin
#define NBINS 391                // ceil(NNODES/BSZ); last bin has 80 nodes
#define CAPE 4992                // fixed per-bin capacity (mean 4092, +14 sd)
#define CLAMP_LO -10.0f
#define CLAMP_HI 10.0f
#define EPS_V 1e-6f

// ---- pass 1: fused transpose (o_pre,E -> (N,16)) + coarse histogram ----
__global__ void prep_hist_kernel(const float* __restrict__ o_pre,
                                 const float* __restrict__ E,
                                 const int* __restrict__ dst,
                                 float* __restrict__ o_t,
                                 float* __restrict__ E_t,
                                 int* __restrict__ hist) {
    __shared__ int lh[NBINS];
    const int tid = threadIdx.x, bid = blockIdx.x;
    for (int i = tid; i < NBINS; i += 256) lh[i] = 0;

    // transpose slice: node t
    int t = bid * 256 + tid;
    if (t < NNODES) {
        float v[BATCH], u[BATCH];
#pragma unroll
        for (int b = 0; b < BATCH; ++b) {
            v[b] = o_pre[b * NNODES + t];  // coalesced across t
            u[b] = E[b * NNODES + t];
        }
        float4* op = (float4*)(o_t + (size_t)t * BATCH);
        float4* ep = (float4*)(E_t + (size_t)t * BATCH);
#pragma unroll
        for (int k = 0; k < 4; ++k) {
            op[k] = make_float4(v[4 * k], v[4 * k + 1], v[4 * k + 2], v[4 * k + 3]);
            ep[k] = make_float4(u[4 * k], u[4 * k + 1], u[4 * k + 2], u[4 * k + 3]);
        }
    }
    __syncthreads();  // lh zeroed

    // histogram slice: int4 edge reads (4 edges / instruction)
    const int4* dst4 = (const int4*)dst;
    const int e4base = bid * (EPB / 4);
#pragma unroll
    for (int j = 0; j < 8; ++j) {
        int i4 = e4base + j * 256 + tid;
        if (i4 * 4 < NEDGES) {  // NEDGES % 4 == 0
            int4 d4 = dst4[i4];
            atomicAdd(&lh[d4.x >> 7], 1);
            atomicAdd(&lh[d4.y >> 7], 1);
            atomicAdd(&lh[d4.z >> 7], 1);
            atomicAdd(&lh[d4.w >> 7], 1);
        }
    }
    __syncthreads();
    for (int i = tid; i < NBINS; i += 256) hist[i * NBLK + bid] = lh[i];
}

// ---- pass 2: per-bin exclusive scan over the 196 block counts ----
__global__ void scanA_kernel(int* __restrict__ hist, int* __restrict__ totals) {
    __shared__ int sm[256];
    int k = blockIdx.x, t = threadIdx.x;
    int v = (t < NBLK) ? hist[k * NBLK + t] : 0;
    sm[t] = v;
    __syncthreads();
    for (int off = 1; off < 256; off <<= 1) {
        int a = (t >= off) ? sm[t - off] : 0;
        __syncthreads();
        sm[t] += a;
        __syncthreads();
    }
    if (t < NBLK) hist[k * NBLK + t] = sm[t] - v;  // exclusive block prefix
    if (t == 0) totals[k] = sm[255];               // bin total (zero-padded)
}

// ---- pass 3: scatter edges into fixed-stride bins, deterministic slots ----
__global__ void scatterA_kernel(const int* __restrict__ src,
                                const int* __restrict__ dst,
                                const float* __restrict__ w,
                                const int* __restrict__ hist,
                                uint2* __restrict__ binned) {
    __shared__ int cur[NBINS];
    const int tid = threadIdx.x, bid = blockIdx.x;
    for (int i = tid; i < NBINS; i += 256)
        cur[i] = i * CAPE + hist[i * NBLK + bid];
    __syncthreads();
    const int4*   dst4 = (const int4*)dst;
    const int4*   src4 = (const int4*)src;
    const float4* w4   = (const float4*)w;
    const int e4base = bid * (EPB / 4);
#pragma unroll
    for (int j = 0; j < 8; ++j) {
        int i4 = e4base + j * 256 + tid;
        if (i4 * 4 < NEDGES) {
            int4 d4 = dst4[i4];
            int4 s4 = src4[i4];
            float4 ww = w4[i4];
            int dd[4] = {d4.x, d4.y, d4.z, d4.w};
            int ss[4] = {s4.x, s4.y, s4.z, s4.w};
            float wv[4] = {ww.x, ww.y, ww.z, ww.w};
#pragma unroll
            for (int m = 0; m < 4; ++m) {
                int d = dd[m];
                int bin = d >> 7;
                int pos = atomicAdd(&cur[bin], 1);  // LDS atomic
                if (pos < (bin + 1) * CAPE)  // overflow guard (never fires)
                    binned[pos] = make_uint2(
                        (unsigned)ss[m] | ((unsigned)(d & 127) << 16),
                        __float_as_uint(wv[m]));
            }
        }
    }
}

// ---- pass 4: per-bin node sub-sort in LDS, register accumulation, epilogue ----
__global__ __launch_bounds__(512) void bin_gather2(
    const float* __restrict__ o_t,
    const float* __restrict__ E_t,
    const float* __restrict__ chem,
    const float* __restrict__ threshold,
    const float* __restrict__ decay,
    const int* __restrict__ totals,
    const uint2* __restrict__ binned,
    float* __restrict__ out_o,
    float* __restrict__ out_e) {
    __shared__ int   cnt_l[BSZ];   // per-node count -> cursor
    __shared__ int   offs[BSZ + 1];
    __shared__ int   sc[BSZ];
    __shared__ uint2 eb[CAPE];     // node-sorted edges of this bin (~40 KB)

    const int k = blockIdx.x, tid = threadIdx.x;
    const int node0 = k * BSZ;
    const int nn = (NNODES - node0 < BSZ) ? (NNODES - node0) : BSZ;
    const int s0 = k * CAPE;
    int cnt = totals[k];
    if (cnt > CAPE) cnt = CAPE;
    const int s1 = s0 + cnt;

    // A1: per-node histogram
    if (tid < BSZ) cnt_l[tid] = 0;
    __syncthreads();
    for (int i = s0 + tid; i < s1; i += 512)
        atomicAdd(&cnt_l[(binned[i].x >> 16) & 127], 1);
    __syncthreads();

    // A2: exclusive scan of 128 counts
    if (tid < BSZ) sc[tid] = cnt_l[tid];
    __syncthreads();
    for (int o = 1; o < BSZ; o <<= 1) {
        int v = (tid >= o && tid < BSZ) ? sc[tid - o] : 0;
        __syncthreads();
        if (tid < BSZ) sc[tid] += v;
        __syncthreads();
    }
    if (tid < BSZ) {
        int ex = sc[tid] - cnt_l[tid];
        offs[tid] = ex;
        cnt_l[tid] = ex;  // cursor
    }
    if (tid == 0) offs[BSZ] = cnt;
    __syncthreads();

    // A3: scatter into node-sorted LDS array
    for (int i = s0 + tid; i < s1; i += 512) {
        uint2 p = binned[i];
        int pos = atomicAdd(&cnt_l[(p.x >> 16) & 127], 1);
        if (pos < CAPE) eb[pos] = p;
    }
    __syncthreads();

    // B+C: one thread per (node, batch-quad); register accumulation; epilogue
    for (int t = tid; t < nn * 4; t += 512) {
        int n = t >> 2;
        int q = (t & 3) * 4;
        int gn = node0 + n;
        int e0 = offs[n], e1 = offs[n + 1];
        float4 en = *(const float4*)(E_t + (size_t)gn * BATCH + q);
        float4 acc = make_float4(0.f, 0.f, 0.f, 0.f);
        for (int i = e0; i < e1; ++i) {
            uint2 p = eb[i];  // 4 lanes of the quad: same address -> broadcast
            float wv = __uint_as_float(p.y);
            int s = (int)(p.x & 0xFFFFu);
            float4 oj = *(const float4*)(o_t + (size_t)s * BATCH + q);
            acc.x += (oj.x >= en.x) ? oj.x * wv : -oj.x * wv;
            acc.y += (oj.y >= en.y) ? oj.y * wv : -oj.y * wv;
            acc.z += (oj.z >= en.z) ? oj.z * wv : -oj.z * wv;
            acc.w += (oj.w >= en.w) ? oj.w * wv : -oj.w * wv;
        }
        float th = threshold[gn];
        float dc = decay[gn];
        float ev[4] = {en.x, en.y, en.z, en.w};
        float av[4] = {acc.x, acc.y, acc.z, acc.w};
#pragma unroll
        for (int j = 0; j < 4; ++j) {
            int b = q + j;
            float e = ev[j];
            float S = e + chem[b * NNODES + gn] + av[j];
            S = fminf(fmaxf(S, CLAMP_LO), CLAMP_HI);
            float no = fmaxf(S - th, 0.0f);
            float ne;
            if (S > th) ne = no;
            else if (fabsf(S - e) <= EPS_V) ne = e - dc;
            else ne = S;
            out_o[b * NNODES + gn] = no;
            out_e[b * NNODES + gn] = ne;
        }
    }
}

// ---------- Fallback: device-scope atomic path (needs no workspace) ----------
__global__ void edge_scatter_dev(const float* __restrict__ o_pre, const float* __restrict__ E,
                                 const float* __restrict__ w, const int* __restrict__ src,
                                 const int* __restrict__ dst, float* __restrict__ gj) {
    int e = blockIdx.x * blockDim.x + threadIdx.x;
    if (e >= NEDGES) return;
    int s = src[e];
    int d = dst[e];
    float wv = w[e];
#pragma unroll
    for (int b = 0; b < BATCH; ++b) {
        float oj = o_pre[b * NNODES + s];
        float en = E[b * NNODES + d];
        atomicAdd(&gj[b * NNODES + d], (oj >= en) ? oj * wv : -oj * wv);
    }
}

__global__ void finalize_dev(const float* __restrict__ chem, const float* __restrict__ E,
                             const float* __restrict__ threshold, const float* __restrict__ decay,
                             float* __restrict__ out_o, float* __restrict__ out_e_gj) {
    int i = blockIdx.x * blockDim.x + threadIdx.x;
    if (i >= BN) return;
    int n = i % NNODES;
    float e = E[i];
    float S = e + chem[i] + out_e_gj[i];
    S = fminf(fmaxf(S, CLAMP_LO), CLAMP_HI);
    float th = threshold[n];
    float no = fmaxf(S - th, 0.0f);
    float ne;
    if (S > th) ne = no;
    else if (fabsf(S - e) <= EPS_V) ne = e - decay[n];
    else ne = S;
    out_o[i] = no;
    out_e_gj[i] = ne;
}

extern "C" void kernel_launch(void* const* d_in, const int* in_sizes, int n_in,
                              void* d_out, int out_size, void* d_ws, size_t ws_size,
                              hipStream_t stream) {
    const float* chem      = (const float*)d_in[0];
    const float* E         = (const float*)d_in[1];
    const float* o_pre     = (const float*)d_in[2];
    const float* w         = (const float*)d_in[3];
    const float* threshold = (const float*)d_in[4];
    const float* decay     = (const float*)d_in[5];
    const int*   src       = (const int*)d_in[6];
    const int*   dst       = (const int*)d_in[7];

    float* out_o = (float*)d_out;
    float* out_e = (float*)d_out + BN;

    // ws layout (bytes, 16B-aligned):
    //   o_t:    [0,          3,200,000)
    //   E_t:    [3,200,000,  6,400,000)
    //   binned: [6,400,000, 22,014,976)   NBINS*CAPE uint2 = 15,614,976 B
    //   hist:   [22,014,976, 22,321,520)  NBINS*NBLK ints
    //   totals: [22,321,536, 22,323,100)  NBINS ints
    const size_t OT_OFF  = 0;
    const size_t ET_OFF  = 3200000;
    const size_t BIN_OFF = 6400000;
    const size_t H_OFF   = 22014976;
    const size_t TOT_OFF = 22321536;
    const size_t need    = TOT_OFF + (size_t)NBINS * sizeof(int);

    if (ws_size >= need) {
        char* ws = (char*)d_ws;
        float* o_t    = (float*)(ws + OT_OFF);
        float* E_t    = (float*)(ws + ET_OFF);
        uint2* binned = (uint2*)(ws + BIN_OFF);
        int*   hist   = (int*)(ws + H_OFF);
        int*   totals = (int*)(ws + TOT_OFF);

        prep_hist_kernel<<<NBLK, 256, 0, stream>>>(o_pre, E, dst, o_t, E_t, hist);
        scanA_kernel<<<NBINS, 256, 0, stream>>>(hist, totals);
        scatterA_kernel<<<NBLK, 256, 0, stream>>>(src, dst, w, hist, binned);
        bin_gather2<<<NBINS, 512, 0, stream>>>(o_t, E_t, chem, threshold, decay,
                                               totals, binned, out_o, out_e);
    } else {
        hipMemsetAsync(out_e, 0, (size_t)BN * sizeof(float), stream);
        edge_scatter_dev<<<(NEDGES + 255) / 256, 256, 0, stream>>>(o_pre, E, w, src, dst, out_e);
        finalize_dev<<<(BN + 255) / 256, 256, 0, stream>>>(chem, E, threshold, decay, out_o, out_e);
    }
}